// Round 1
// baseline (282.476 us; speedup 1.0000x reference)
//
#include <hip/hip_runtime.h>
#include <math.h>

// Problem constants (from reference): B=16, T=16, FDIM=64, ODIM=8,
// NQ=10, NA=4, TOT=14, LAYERS=2, DEGREE=3, NROTS=80, QROTS=40.
// State layout in workspace: float2 state[b][a][n], b<16, a<16, n<1024.
// Qubit w (w<10) <-> bit (9-w) of n. Ancilla qubit NQ+qi <-> bit (3-qi) of a.
// Workspace needed: 2 MB state + 80 KB ts + ~6.3 KB matrices (~2.2 MB total).

struct Gate { int ry; int tbit; int cbit; int pidx; };
struct GateTab { Gate g[80]; };

// sim14_seq(10, 2) compiled to a gate table. tbit/cbit are bit positions in n.
constexpr GateTab make_gates() {
  GateTab tb{};
  int pos = 0, idx = 0;
  for (int l = 0; l < 2; ++l) {
    for (int i = 0; i < 10; ++i) { tb.g[pos] = Gate{1, 9 - i, -1, idx}; ++pos; ++idx; }
    for (int i = 9; i >= 0; --i) { tb.g[pos] = Gate{0, 9 - ((i + 1) % 10), 9 - i, idx}; ++pos; ++idx; }
    for (int i = 0; i < 10; ++i) { tb.g[pos] = Gate{1, 9 - i, -1, idx}; ++pos; ++idx; }
    for (int k = 0; k < 10; ++k) {
      int i = (k == 0) ? 9 : (k - 1);
      tb.g[pos] = Gate{0, 9 - ((i + 9) % 10), 9 - i, idx}; ++pos; ++idx;
    }
  }
  return tb;
}

__constant__ GateTab GT = make_gates();

__device__ __forceinline__ int insert_zero(int v, int p) {
  return ((v >> p) << (p + 1)) | (v & ((1 << p) - 1));
}

__device__ __forceinline__ float2 cmul(float2 A, float2 B) {
  return make_float2(A.x * B.x - A.y * B.y, A.x * B.y + A.y * B.x);
}
__device__ __forceinline__ float2 conj2(float2 A) { return make_float2(A.x, -A.y); }
__device__ __forceinline__ float2 cfma(float2 A, float2 B, float2 acc) {
  acc.x += A.x * B.x - A.y * B.y;
  acc.y += A.x * B.y + A.y * B.x;
  return acc;
}

// Apply one gate to a 1024-amplitude LDS state, 256 threads cooperating.
// ry: new0 = c*a0 - s*a1 ; new1 = s*a0 + c*a1   (real coefficients)
// crx (ctrl=1 subspace): new0 = c*a0 + (-i s)*a1 ; new1 = (-i s)*a0 + c*a1
__device__ __forceinline__ void apply_gate_lds(float2* amp, Gate G, float theta, int tid) {
  float s, c;
  sincosf(0.5f * theta, &s, &c);
  if (G.cbit < 0) {
    int p = G.tbit;
#pragma unroll
    for (int r = 0; r < 2; ++r) {
      int pp = tid + (r << 8);            // 512 pairs
      int n0 = insert_zero(pp, p);
      int n1 = n0 | (1 << p);
      float2 a0 = amp[n0], a1 = amp[n1];
      amp[n0] = make_float2(c * a0.x - s * a1.x, c * a0.y - s * a1.y);
      amp[n1] = make_float2(s * a0.x + c * a1.x, s * a0.y + c * a1.y);
    }
  } else {
    int pc = G.cbit, pt = G.tbit;
    int lo = pc < pt ? pc : pt;
    int hi = pc < pt ? pt : pc;
    int m = insert_zero(tid, lo);         // 256 pairs (ctrl=1 subspace)
    m = insert_zero(m, hi);
    int n0 = m | (1 << pc);
    int n1 = n0 | (1 << pt);
    float2 a0 = amp[n0], a1 = amp[n1];
    // (-i s)*(x+iy) = (s*y, -s*x)
    amp[n0] = make_float2(c * a0.x + s * a1.y, c * a0.y - s * a1.x);
    amp[n1] = make_float2(c * a1.x + s * a0.y, c * a1.y - s * a0.x);
  }
}

// ts = sigmoid((x^T + pe) @ W_fp^T + b_fp) * 2pi.  One block per (b,t).
__global__ __launch_bounds__(128) void k_ts(const float* __restrict__ x,
                                            const float* __restrict__ W,
                                            const float* __restrict__ bias,
                                            float* __restrict__ ts) {
  int blk = blockIdx.x;            // b*16 + t
  int b = blk >> 4, t = blk & 15;
  __shared__ float h[64];
  int tid = threadIdx.x;
  if (tid < 64) {
    int f = tid, k = f >> 1;
    float div = expf(-(float)(2 * k) * (logf(10000.f) / 64.f));
    float ang = (float)t * div;
    float pe = (f & 1) ? cosf(ang) : sinf(ang);
    h[f] = x[(b * 64 + f) * 16 + t] + pe;
  }
  __syncthreads();
  if (tid < 80) {
    float acc = bias[tid];
    const float* wr = W + tid * 64;
#pragma unroll 8
    for (int f = 0; f < 64; ++f) acc += h[f] * wr[f];
    float sg = 1.f / (1.f + expf(-acc));
    ts[blk * 80 + tid] = sg * 6.2831853071795864769f;
  }
}

// Build the 16x16 ancilla matrices from prep_p and sig_ang.
// mats layout (float2): [0..15] M0col = (U_prep . D0)[:,0]
//                       [16..271]  Mmid1 = U D1 U^dag
//                       [272..527] Mmid2 = U D2 U^dag
//                       [528..783] Mend  = D3 U^dag
__global__ __launch_bounds__(256) void k_build(const float* __restrict__ prep,
                                               const float* __restrict__ sig,
                                               float2* __restrict__ mats) {
  __shared__ float2 U[256];        // U[a*16 + j] : column j = U_prep e_j
  int tid = threadIdx.x;
  U[tid] = make_float2((tid >> 4) == (tid & 15) ? 1.f : 0.f, 0.f);
  __syncthreads();
  for (int ly = 0; ly < 4; ++ly) {
    for (int qi = 0; qi < 4; ++qi) {
      int p = 3 - qi;
      // ry
      float th = prep[ly * 8 + qi * 2 + 0];
      float s, c;
      sincosf(0.5f * th, &s, &c);
      if (tid < 128) {
        int j = tid & 15, pp = tid >> 4;           // 8 pairs x 16 cols
        int a0 = insert_zero(pp, p), a1 = a0 | (1 << p);
        float2 u0 = U[a0 * 16 + j], u1 = U[a1 * 16 + j];
        U[a0 * 16 + j] = make_float2(c * u0.x - s * u1.x, c * u0.y - s * u1.y);
        U[a1 * 16 + j] = make_float2(s * u0.x + c * u1.x, s * u0.y + c * u1.y);
      }
      __syncthreads();
      // rz: diag(e^{-i th/2}, e^{+i th/2})
      th = prep[ly * 8 + qi * 2 + 1];
      sincosf(0.5f * th, &s, &c);
      if (tid < 128) {
        int j = tid & 15, pp = tid >> 4;
        int a0 = insert_zero(pp, p), a1 = a0 | (1 << p);
        float2 u0 = U[a0 * 16 + j], u1 = U[a1 * 16 + j];
        U[a0 * 16 + j] = make_float2(c * u0.x + s * u0.y, c * u0.y - s * u0.x);
        U[a1 * 16 + j] = make_float2(c * u1.x - s * u1.y, c * u1.y + s * u1.x);
      }
      __syncthreads();
    }
    for (int i = 0; i < 3; ++i) {                  // CNOT chain
      int pc = 3 - i, pt = 2 - i;                  // pt < pc
      if (tid < 64) {
        int j = tid & 15, pp = tid >> 4;           // 4 pairs x 16 cols
        int m = insert_zero(pp, pt);
        m = insert_zero(m, pc);
        int a0 = m | (1 << pc), a1 = a0 | (1 << pt);
        float2 t0 = U[a0 * 16 + j], t1 = U[a1 * 16 + j];
        U[a0 * 16 + j] = t1;
        U[a1 * 16 + j] = t0;
      }
      __syncthreads();
    }
  }
  // D_k = diag over a: a==0 -> e^{i phi_k}, else e^{-i phi_k}
  int a = tid >> 4, bb = tid & 15;
  float2 e1, e2, e3;
  sincosf(sig[1], &e1.y, &e1.x);
  sincosf(sig[2], &e2.y, &e2.x);
  sincosf(sig[3], &e3.y, &e3.x);
  float2 acc1 = make_float2(0.f, 0.f), acc2 = make_float2(0.f, 0.f);
  for (int cix = 0; cix < 16; ++cix) {
    float2 t = cmul(U[a * 16 + cix], conj2(U[bb * 16 + cix]));
    acc1 = cfma(t, (cix == 0) ? e1 : conj2(e1), acc1);
    acc2 = cfma(t, (cix == 0) ? e2 : conj2(e2), acc2);
  }
  mats[16 + tid] = acc1;
  mats[272 + tid] = acc2;
  float2 v3 = (a == 0) ? e3 : conj2(e3);
  mats[528 + tid] = cmul(v3, conj2(U[bb * 16 + a]));
  if (tid < 16) {
    float2 e0;
    sincosf(sig[0], &e0.y, &e0.x);
    mats[tid] = cmul(U[tid * 16 + 0], e0);
  }
}

// sim14(LAYERS=2) on one (b,a) column of 1024 amplitudes. One block per column.
__global__ __launch_bounds__(256) void k_select(float2* __restrict__ state,
                                                const float* __restrict__ ts,
                                                const float2* __restrict__ m0col,
                                                int adjoint, int initFrom0) {
  int blk = blockIdx.x, tid = threadIdx.x;   // blk = b*16 + a
  __shared__ float2 amp[1024];
  __shared__ float th[80];
  if (tid < 80) th[tid] = ts[blk * 80 + tid];
  float2* g = state + blk * 1024;
  if (initFrom0) {
    for (int i = tid; i < 1024; i += 256) amp[i] = make_float2(0.f, 0.f);
    if (tid == 0) amp[0] = m0col[blk & 15];
  } else {
    for (int i = tid; i < 1024; i += 256) amp[i] = g[i];
  }
  float sgn = adjoint ? -1.f : 1.f;
  for (int gg = 0; gg < 80; ++gg) {
    __syncthreads();
    int gi = adjoint ? (79 - gg) : gg;
    Gate G = GT.g[gi];
    apply_gate_lds(amp, G, sgn * th[G.pidx], tid);
  }
  __syncthreads();
  for (int i = tid; i < 1024; i += 256) g[i] = amp[i];
}

// qff: sim14(layers=1) with shared scalar params, forward. One block per column.
__global__ __launch_bounds__(256) void k_qff(float2* __restrict__ state,
                                             const float* __restrict__ qff) {
  int blk = blockIdx.x, tid = threadIdx.x;
  __shared__ float2 amp[1024];
  __shared__ float th[40];
  if (tid < 40) th[tid] = qff[tid];
  float2* g = state + blk * 1024;
  for (int i = tid; i < 1024; i += 256) amp[i] = g[i];
  for (int gg = 0; gg < 40; ++gg) {
    __syncthreads();
    Gate G = GT.g[gg];
    apply_gate_lds(amp, G, th[G.pidx], tid);
  }
  __syncthreads();
  for (int i = tid; i < 1024; i += 256) g[i] = amp[i];
}

// In-place ancilla-space matmul: psi[b][:, n] <- M (16x16) * psi[b][:, n].
// Each thread owns one (b,n) slice -> no cross-thread hazard, in-place safe.
__global__ __launch_bounds__(256) void k_anc(float2* __restrict__ state,
                                             const float2* __restrict__ M) {
  __shared__ float2 sM[256];
  int tid = threadIdx.x;
  sM[tid] = M[tid];
  __syncthreads();
  int t = blockIdx.x * 256 + tid;   // t < 16*1024
  int b = t >> 10, n = t & 1023;
  float2* p = state + b * 16384 + n;
  float2 v[16];
#pragma unroll
  for (int ap = 0; ap < 16; ++ap) v[ap] = p[ap << 10];
#pragma unroll
  for (int ao = 0; ao < 16; ++ao) {
    float re = 0.f, im = 0.f;
#pragma unroll
    for (int ap = 0; ap < 16; ++ap) {
      float2 m = sM[ao * 16 + ap];
      re += m.x * v[ap].x - m.y * v[ap].y;
      im += m.x * v[ap].y + m.y * v[ap].x;
    }
    p[ao << 10] = make_float2(re, im);
  }
}

__device__ __forceinline__ float wave_sum(float v) {
  for (int off = 32; off > 0; off >>= 1) v += __shfl_down(v, off);
  return v;
}

// expvals (X,Y,Z on qubits 0..9) + out = exps @ W_out^T + b_out. One block per b.
__global__ __launch_bounds__(256) void k_exp(const float2* __restrict__ state,
                                             const float* __restrict__ Wout,
                                             const float* __restrict__ bout,
                                             float* __restrict__ out) {
  int b = blockIdx.x, tid = threadIdx.x;
  const float2* S = state + b * 16384;
  __shared__ float wsum[4][30];
  __shared__ float sv[30];
  int lane = tid & 63, wid = tid >> 6;
  for (int i = 0; i < 10; ++i) {
    int p = 9 - i;
    float cr = 0.f, ci = 0.f, zz = 0.f;
    for (int idx = tid; idx < 8192; idx += 256) {
      int a = idx >> 9, pp = idx & 511;
      int n0 = insert_zero(pp, p);
      const float2* base = S + (a << 10);
      float2 A0 = base[n0];
      float2 A1 = base[n0 + (1 << p)];
      cr += A0.x * A1.x + A0.y * A1.y;          // Re(conj(s0)*s1)
      ci += A0.x * A1.y - A0.y * A1.x;          // Im(conj(s0)*s1)
      zz += (A0.x * A0.x + A0.y * A0.y) - (A1.x * A1.x + A1.y * A1.y);
    }
    cr = wave_sum(cr);
    ci = wave_sum(ci);
    zz = wave_sum(zz);
    if (lane == 0) {
      wsum[wid][i] = 2.f * cr;
      wsum[wid][10 + i] = 2.f * ci;
      wsum[wid][20 + i] = zz;
    }
  }
  __syncthreads();
  if (tid < 30) sv[tid] = wsum[0][tid] + wsum[1][tid] + wsum[2][tid] + wsum[3][tid];
  __syncthreads();
  if (tid < 8) {
    float acc = bout[tid];
#pragma unroll
    for (int j = 0; j < 30; ++j) acc += Wout[tid * 30 + j] * sv[j];
    out[b * 8 + tid] = acc;
  }
}

extern "C" void kernel_launch(void* const* d_in, const int* in_sizes, int n_in,
                              void* d_out, int out_size, void* d_ws, size_t ws_size,
                              hipStream_t stream) {
  const float* x     = (const float*)d_in[0];  // (16,64,16)
  const float* W_fp  = (const float*)d_in[1];  // (80,64)
  const float* b_fp  = (const float*)d_in[2];  // (80,)
  const float* prep  = (const float*)d_in[3];  // (4,4,2)
  const float* sig   = (const float*)d_in[4];  // (4,)
  const float* qff   = (const float*)d_in[5];  // (40,)
  const float* W_out = (const float*)d_in[6];  // (8,30)
  const float* b_out = (const float*)d_in[7];  // (8,)
  float* out = (float*)d_out;                  // (16,8) float32

  char* ws = (char*)d_ws;
  float2* state = (float2*)ws;                          // 16*16384 float2 = 2 MB
  float*  ts    = (float*)(ws + 2097152);               // 256*80 floats = 80 KB
  float2* mats  = (float2*)(ws + 2097152 + 81920);      // 784 float2

  k_ts<<<256, 128, 0, stream>>>(x, W_fp, b_fp, ts);
  k_build<<<1, 256, 0, stream>>>(prep, sig, mats);
  // k=0: init from M0col, forward select
  k_select<<<256, 256, 0, stream>>>(state, ts, mats, 0, 1);
  k_anc<<<64, 256, 0, stream>>>(state, mats + 16);      // U D1 U^dag
  // k=1: adjoint select
  k_select<<<256, 256, 0, stream>>>(state, ts, mats, 1, 0);
  k_anc<<<64, 256, 0, stream>>>(state, mats + 272);     // U D2 U^dag
  // k=2: forward select
  k_select<<<256, 256, 0, stream>>>(state, ts, mats, 0, 0);
  k_anc<<<64, 256, 0, stream>>>(state, mats + 528);     // D3 U^dag
  k_qff<<<256, 256, 0, stream>>>(state, qff);
  k_exp<<<16, 256, 0, stream>>>(state, W_out, b_out, out);
}

// Round 2
// 207.323 us; speedup vs baseline: 1.3625x; 1.3625x over previous
//
#include <hip/hip_runtime.h>
#include <math.h>
#include <utility>

// B=16, T=16, FDIM=64, ODIM=8, NQ=10, NA=4, LAYERS=2, DEGREE=3.
// State: float2 state[b][a][n], n<1024 (qubit i <-> bit 9-i of n), a<16
// (ancilla qubit NQ+qi <-> bit 3-qi of a).
// Wave-resident select: one 64-lane wave owns one (b,a) column.
// Amp mapping: n = lane*16 + r  (bits [3:0]=r in-thread, [9:4]=lane).
// Gates on bit<4: thread-local. Gates on bit>=4: __shfl_xor butterfly.

struct Gate { int ry; int tbit; int cbit; int pidx; };
struct GateTab { Gate g[40]; };

// One sim14 layer (NQ=10) as a compile-time gate table.
constexpr GateTab make_gates1() {
  GateTab tb{};
  int pos = 0, idx = 0;
  for (int i = 0; i < 10; ++i) { tb.g[pos] = Gate{1, 9 - i, -1, idx}; ++pos; ++idx; }
  for (int i = 9; i >= 0; --i) { tb.g[pos] = Gate{0, 9 - ((i + 1) % 10), 9 - i, idx}; ++pos; ++idx; }
  for (int i = 0; i < 10; ++i) { tb.g[pos] = Gate{1, 9 - i, -1, idx}; ++pos; ++idx; }
  for (int k = 0; k < 10; ++k) {
    int i = (k == 0) ? 9 : (k - 1);
    tb.g[pos] = Gate{0, 9 - ((i + 9) % 10), 9 - i, idx}; ++pos; ++idx;
  }
  return tb;
}
constexpr GateTab GTC = make_gates1();

__device__ __forceinline__ int insert_zero(int v, int p) {
  return ((v >> p) << (p + 1)) | (v & ((1 << p) - 1));
}
__device__ __forceinline__ float2 cmul(float2 A, float2 B) {
  return make_float2(A.x * B.x - A.y * B.y, A.x * B.y + A.y * B.x);
}
__device__ __forceinline__ float2 conj2(float2 A) { return make_float2(A.x, -A.y); }
__device__ __forceinline__ float2 cfma(float2 A, float2 B, float2 acc) {
  acc.x += A.x * B.x - A.y * B.y;
  acc.y += A.x * B.y + A.y * B.x;
  return acc;
}

// ---------------- register/shuffle gate engine ----------------
// ry:  new0 = c*a0 - s*a1 ; new1 = s*a0 + c*a1
template<int P>
__device__ __forceinline__ void ry_gate(float2 (&a)[16], float c, float s, int lane) {
  if constexpr (P < 4) {
    constexpr int m = 1 << P;
#pragma unroll
    for (int r0 = 0; r0 < 16; ++r0) {
      if (!(r0 & m)) {
        int r1 = r0 | m;
        float2 a0 = a[r0], a1 = a[r1];
        a[r0] = make_float2(c * a0.x - s * a1.x, c * a0.y - s * a1.y);
        a[r1] = make_float2(s * a0.x + c * a1.x, s * a0.y + c * a1.y);
      }
    }
  } else {
    constexpr int xm = 1 << (P - 4);
    bool up = (lane >> (P - 4)) & 1;
    float sg = up ? s : -s;      // v' = c*v + (mybit? +s : -s)*partner
#pragma unroll
    for (int r = 0; r < 16; ++r) {
      float wx = __shfl_xor(a[r].x, xm, 64);
      float wy = __shfl_xor(a[r].y, xm, 64);
      a[r].x = c * a[r].x + sg * wx;
      a[r].y = c * a[r].y + sg * wy;
    }
  }
}

// crx (ctrl bit Q must be 1): v' = c*v + (-i s)*w  (same form both sides)
//   v'.x = c*v.x + s*w.y ; v'.y = c*v.y - s*w.x
template<int P, int Q>
__device__ __forceinline__ void crx_gate(float2 (&a)[16], float c, float s, int lane) {
  if constexpr (P < 4) {
    constexpr int m = 1 << P;
#pragma unroll
    for (int r0 = 0; r0 < 16; ++r0) {
      if (!(r0 & m)) {
        int r1 = r0 | m;
        bool act;
        if constexpr (Q < 4) act = (r0 >> Q) & 1;
        else act = (lane >> (Q - 4)) & 1;
        if (act) {
          float2 a0 = a[r0], a1 = a[r1];
          a[r0] = make_float2(c * a0.x + s * a1.y, c * a0.y - s * a1.x);
          a[r1] = make_float2(c * a1.x + s * a0.y, c * a1.y - s * a0.x);
        }
      }
    }
  } else {
    constexpr int xm = 1 << (P - 4);
#pragma unroll
    for (int r = 0; r < 16; ++r) {
      float wx = __shfl_xor(a[r].x, xm, 64);
      float wy = __shfl_xor(a[r].y, xm, 64);
      bool act;
      if constexpr (Q < 4) act = (r >> Q) & 1;
      else act = (lane >> (Q - 4)) & 1;
      if (act) {
        float nx = c * a[r].x + s * wy;
        float ny = c * a[r].y - s * wx;
        a[r].x = nx; a[r].y = ny;
      }
    }
  }
}

template<bool ADJ, int G>
__device__ __forceinline__ void one_gate(float2 (&a)[16], const float2* __restrict__ sc, int lane) {
  constexpr Gate g = GTC.g[ADJ ? (39 - G) : G];
  float2 scv = sc[g.pidx];          // (sin(th/2), cos(th/2)), wave-uniform
  float s = ADJ ? -scv.x : scv.x;
  float c = scv.y;
  if constexpr (g.ry != 0) ry_gate<g.tbit>(a, c, s, lane);
  else crx_gate<g.tbit, g.cbit>(a, c, s, lane);
}

template<bool ADJ, int... I>
__device__ __forceinline__ void run_layer_impl(float2 (&a)[16], const float2* __restrict__ sc,
                                               int lane, std::integer_sequence<int, I...>) {
  (one_gate<ADJ, I>(a, sc, lane), ...);
}
template<bool ADJ>
__device__ __forceinline__ void run_layer(float2 (&a)[16], const float2* __restrict__ sc, int lane) {
  run_layer_impl<ADJ>(a, sc, lane, std::make_integer_sequence<int, 40>{});
}

// Mix: a[r] = sum_ap M[aa][ap] * src[b][ap][lane*16+r]
__device__ __forceinline__ void mix_load(float2 (&a)[16], const float2* __restrict__ src,
                                         const float2* __restrict__ M, int b, int aa, int lane) {
#pragma unroll
  for (int r = 0; r < 16; ++r) a[r] = make_float2(0.f, 0.f);
#pragma unroll
  for (int ap = 0; ap < 16; ++ap) {
    float2 m = M[aa * 16 + ap];
    const float4* col4 = (const float4*)(src + (size_t)(b * 16 + ap) * 1024) + lane * 8;
#pragma unroll
    for (int q = 0; q < 8; ++q) {
      float4 v = col4[q];
      a[2 * q].x     += m.x * v.x - m.y * v.y;
      a[2 * q].y     += m.x * v.y + m.y * v.x;
      a[2 * q + 1].x += m.x * v.z - m.y * v.w;
      a[2 * q + 1].y += m.x * v.w + m.y * v.z;
    }
  }
}

// ---------------- kernels ----------------

// tsc[(b*16+t)*80+j] = (sin, cos) of sigmoid(h@W^T+b)*pi. One block per (b,t).
__global__ __launch_bounds__(128) void k_ts(const float* __restrict__ x,
                                            const float* __restrict__ W,
                                            const float* __restrict__ bias,
                                            float2* __restrict__ tsc) {
  int blk = blockIdx.x;            // b*16 + t
  int b = blk >> 4, t = blk & 15;
  __shared__ float h[64];
  int tid = threadIdx.x;
  if (tid < 64) {
    int f = tid, k = f >> 1;
    float div = expf(-(float)(2 * k) * (logf(10000.f) / 64.f));
    float ang = (float)t * div;
    float pe = (f & 1) ? cosf(ang) : sinf(ang);
    h[f] = x[(b * 64 + f) * 16 + t] + pe;
  }
  __syncthreads();
  if (tid < 80) {
    float acc = bias[tid];
    const float* wr = W + tid * 64;
#pragma unroll 8
    for (int f = 0; f < 64; ++f) acc += h[f] * wr[f];
    float sg = 1.f / (1.f + expf(-acc));
    float s, c;
    sincosf(sg * 3.14159265358979323846f, &s, &c);   // theta/2 = sigmoid*pi
    tsc[blk * 80 + tid] = make_float2(s, c);
  }
}

// 16x16 ancilla matrices + qff sincos.
// mats (float2): [0..15] M0col=(U D0)[:,0]; [16..271] U D1 U^dag;
//                [272..527] U D2 U^dag; [528..783] D3 U^dag.
__global__ __launch_bounds__(256) void k_build(const float* __restrict__ prep,
                                               const float* __restrict__ sig,
                                               const float* __restrict__ qffp,
                                               float2* __restrict__ mats,
                                               float2* __restrict__ qsc) {
  __shared__ float2 U[256];        // U[a*16 + j]
  int tid = threadIdx.x;
  if (tid < 40) {
    float s, c;
    sincosf(0.5f * qffp[tid], &s, &c);
    qsc[tid] = make_float2(s, c);
  }
  U[tid] = make_float2((tid >> 4) == (tid & 15) ? 1.f : 0.f, 0.f);
  __syncthreads();
  for (int ly = 0; ly < 4; ++ly) {
    for (int qi = 0; qi < 4; ++qi) {
      int p = 3 - qi;
      float th = prep[ly * 8 + qi * 2 + 0];
      float s, c;
      sincosf(0.5f * th, &s, &c);
      if (tid < 128) {
        int j = tid & 15, pp = tid >> 4;
        int a0 = insert_zero(pp, p), a1 = a0 | (1 << p);
        float2 u0 = U[a0 * 16 + j], u1 = U[a1 * 16 + j];
        U[a0 * 16 + j] = make_float2(c * u0.x - s * u1.x, c * u0.y - s * u1.y);
        U[a1 * 16 + j] = make_float2(s * u0.x + c * u1.x, s * u0.y + c * u1.y);
      }
      __syncthreads();
      th = prep[ly * 8 + qi * 2 + 1];
      sincosf(0.5f * th, &s, &c);
      if (tid < 128) {
        int j = tid & 15, pp = tid >> 4;
        int a0 = insert_zero(pp, p), a1 = a0 | (1 << p);
        float2 u0 = U[a0 * 16 + j], u1 = U[a1 * 16 + j];
        U[a0 * 16 + j] = make_float2(c * u0.x + s * u0.y, c * u0.y - s * u0.x);
        U[a1 * 16 + j] = make_float2(c * u1.x - s * u1.y, c * u1.y + s * u1.x);
      }
      __syncthreads();
    }
    for (int i = 0; i < 3; ++i) {
      int pc = 3 - i, pt = 2 - i;
      if (tid < 64) {
        int j = tid & 15, pp = tid >> 4;
        int m = insert_zero(pp, pt);
        m = insert_zero(m, pc);
        int a0 = m | (1 << pc), a1 = a0 | (1 << pt);
        float2 t0 = U[a0 * 16 + j], t1 = U[a1 * 16 + j];
        U[a0 * 16 + j] = t1;
        U[a1 * 16 + j] = t0;
      }
      __syncthreads();
    }
  }
  int a = tid >> 4, bb = tid & 15;
  float2 e1, e2, e3;
  sincosf(sig[1], &e1.y, &e1.x);
  sincosf(sig[2], &e2.y, &e2.x);
  sincosf(sig[3], &e3.y, &e3.x);
  float2 acc1 = make_float2(0.f, 0.f), acc2 = make_float2(0.f, 0.f);
  for (int cix = 0; cix < 16; ++cix) {
    float2 t = cmul(U[a * 16 + cix], conj2(U[bb * 16 + cix]));
    acc1 = cfma(t, (cix == 0) ? e1 : conj2(e1), acc1);
    acc2 = cfma(t, (cix == 0) ? e2 : conj2(e2), acc2);
  }
  mats[16 + tid] = acc1;
  mats[272 + tid] = acc2;
  float2 v3 = (a == 0) ? e3 : conj2(e3);
  mats[528 + tid] = cmul(v3, conj2(U[bb * 16 + a]));
  if (tid < 16) {
    float2 e0;
    sincosf(sig[0], &e0.y, &e0.x);
    mats[tid] = cmul(U[tid * 16 + 0], e0);
  }
}

// Select: one wave per (b,a) column, 80 gates register-resident.
// MODE 0: init column from m0col. MODE 1: load own column. MODE 2: ancilla-mix
// from src (reads 16 columns of b; must write to a DIFFERENT buffer).
template<bool ADJ, int MODE>
__global__ __launch_bounds__(64) void k_sel(const float2* __restrict__ src,
                                            float2* __restrict__ dst,
                                            const float2* __restrict__ sc_ts,
                                            const float2* __restrict__ mat) {
  int blk = blockIdx.x, lane = threadIdx.x;   // blk = b*16 + a
  const float2* __restrict__ sc = sc_ts + blk * 80;
  float2 a[16];
  if constexpr (MODE == 0) {
#pragma unroll
    for (int r = 0; r < 16; ++r) a[r] = make_float2(0.f, 0.f);
    if (lane == 0) a[0] = mat[blk & 15];
  } else if constexpr (MODE == 1) {
    const float4* g4 = (const float4*)(src + (size_t)blk * 1024) + lane * 8;
#pragma unroll
    for (int q = 0; q < 8; ++q) {
      float4 v = g4[q];
      a[2 * q]     = make_float2(v.x, v.y);
      a[2 * q + 1] = make_float2(v.z, v.w);
    }
  } else {
    mix_load(a, src, mat, blk >> 4, blk & 15, lane);
  }
  if constexpr (ADJ) {
    run_layer<true>(a, sc + 40, lane);
    run_layer<true>(a, sc, lane);
  } else {
    run_layer<false>(a, sc, lane);
    run_layer<false>(a, sc + 40, lane);
  }
  float4* o4 = (float4*)(dst + (size_t)blk * 1024) + lane * 8;
#pragma unroll
  for (int q = 0; q < 8; ++q)
    o4[q] = make_float4(a[2 * q].x, a[2 * q].y, a[2 * q + 1].x, a[2 * q + 1].y);
}

// Final: mix with Mend, 40 qff gates, expvals partials -> atomicAdd sv[b][30].
__global__ __launch_bounds__(64) void k_qff_exp(const float2* __restrict__ src,
                                                const float2* __restrict__ mend,
                                                const float2* __restrict__ qsc,
                                                float* __restrict__ sv) {
  int blk = blockIdx.x, lane = threadIdx.x;
  int b = blk >> 4, aa = blk & 15;
  float2 a[16];
  mix_load(a, src, mend, b, aa, lane);
  run_layer<false>(a, qsc, lane);
  float obs[30];
#pragma unroll
  for (int p = 0; p <= 9; ++p) {
    int i = 9 - p;                  // qubit index
    float cr = 0.f, ci = 0.f, zz = 0.f;
    if (p < 4) {
      int m = 1 << p;
#pragma unroll
      for (int r0 = 0; r0 < 16; ++r0) {
        if (!(r0 & m)) {
          float2 A0 = a[r0], A1 = a[r0 | m];
          cr += A0.x * A1.x + A0.y * A1.y;
          ci += A0.x * A1.y - A0.y * A1.x;
          zz += (A0.x * A0.x + A0.y * A0.y) - (A1.x * A1.x + A1.y * A1.y);
        }
      }
    } else {
      int xm = 1 << (p - 4);
      bool up = (lane >> (p - 4)) & 1;
#pragma unroll
      for (int r = 0; r < 16; ++r) {
        float wx = __shfl_xor(a[r].x, xm, 64);
        float wy = __shfl_xor(a[r].y, xm, 64);
        float n2 = a[r].x * a[r].x + a[r].y * a[r].y;
        if (!up) {
          cr += a[r].x * wx + a[r].y * wy;
          ci += a[r].x * wy - a[r].y * wx;
          zz += n2;
        } else {
          zz -= n2;
        }
      }
    }
    obs[i] = 2.f * cr;
    obs[10 + i] = 2.f * ci;
    obs[20 + i] = zz;
  }
#pragma unroll
  for (int j = 0; j < 30; ++j) {
    float v = obs[j];
    for (int off = 32; off; off >>= 1) v += __shfl_down(v, off, 64);
    if (lane == 0) atomicAdd(&sv[b * 30 + j], v);
  }
}

// out[b][o] = b_out[o] + sum_j W_out[o][j] * sv[b][j]. One block, 128 threads.
__global__ __launch_bounds__(128) void k_out(const float* __restrict__ sv,
                                             const float* __restrict__ W,
                                             const float* __restrict__ bo,
                                             float* __restrict__ out) {
  int tid = threadIdx.x;            // b*8 + o
  int b = tid >> 3, o = tid & 7;
  float acc = bo[o];
#pragma unroll
  for (int j = 0; j < 30; ++j) acc += W[o * 30 + j] * sv[b * 30 + j];
  out[tid] = acc;
}

// Fallback in-place ancilla matmul (used when ws too small for ping-pong).
__global__ __launch_bounds__(256) void k_anc(float2* __restrict__ state,
                                             const float2* __restrict__ M) {
  __shared__ float2 sM[256];
  int tid = threadIdx.x;
  sM[tid] = M[tid];
  __syncthreads();
  int t = blockIdx.x * 256 + tid;
  int b = t >> 10, n = t & 1023;
  float2* p = state + b * 16384 + n;
  float2 v[16];
#pragma unroll
  for (int ap = 0; ap < 16; ++ap) v[ap] = p[ap << 10];
#pragma unroll
  for (int ao = 0; ao < 16; ++ao) {
    float re = 0.f, im = 0.f;
#pragma unroll
    for (int ap = 0; ap < 16; ++ap) {
      float2 m = sM[ao * 16 + ap];
      re += m.x * v[ap].x - m.y * v[ap].y;
      im += m.x * v[ap].y + m.y * v[ap].x;
    }
    p[ao << 10] = make_float2(re, im);
  }
}

extern "C" void kernel_launch(void* const* d_in, const int* in_sizes, int n_in,
                              void* d_out, int out_size, void* d_ws, size_t ws_size,
                              hipStream_t stream) {
  const float* x     = (const float*)d_in[0];
  const float* W_fp  = (const float*)d_in[1];
  const float* b_fp  = (const float*)d_in[2];
  const float* prep  = (const float*)d_in[3];
  const float* sig   = (const float*)d_in[4];
  const float* qff   = (const float*)d_in[5];
  const float* W_out = (const float*)d_in[6];
  const float* b_out = (const float*)d_in[7];
  float* out = (float*)d_out;

  char* ws = (char*)d_ws;
  const size_t SZ_STATE = 2097152;      // 256 cols * 1024 * 8 B
  const size_t SZ_TSC   = 163840;       // 256*80 float2
  const size_t SZ_MATS  = 6272;         // 784 float2
  const size_t SZ_QSC   = 320;          // 40 float2
  const size_t SZ_SV    = 1920;         // 16*30 float
  bool pp = ws_size >= 2 * SZ_STATE + SZ_TSC + SZ_MATS + SZ_QSC + SZ_SV;

  float2* state0 = (float2*)ws;
  float2* state1 = pp ? (float2*)(ws + SZ_STATE) : nullptr;
  char* tail = ws + (pp ? 2 * SZ_STATE : SZ_STATE);
  float2* tsc  = (float2*)tail;
  float2* mats = (float2*)(tail + SZ_TSC);
  float2* qsc  = (float2*)(tail + SZ_TSC + SZ_MATS);
  float*  sv   = (float*) (tail + SZ_TSC + SZ_MATS + SZ_QSC);

  hipMemsetAsync(sv, 0, SZ_SV, stream);
  k_ts<<<256, 128, 0, stream>>>(x, W_fp, b_fp, tsc);
  k_build<<<1, 256, 0, stream>>>(prep, sig, qff, mats, qsc);

  if (pp) {
    k_sel<false, 0><<<256, 64, 0, stream>>>(nullptr, state0, tsc, mats);        // init+sel fwd
    k_sel<true,  2><<<256, 64, 0, stream>>>(state0, state1, tsc, mats + 16);    // mix M1 + adj
    k_sel<false, 2><<<256, 64, 0, stream>>>(state1, state0, tsc, mats + 272);   // mix M2 + fwd
  } else {
    k_sel<false, 0><<<256, 64, 0, stream>>>(nullptr, state0, tsc, mats);
    k_anc<<<64, 256, 0, stream>>>(state0, mats + 16);
    k_sel<true,  1><<<256, 64, 0, stream>>>(state0, state0, tsc, nullptr);
    k_anc<<<64, 256, 0, stream>>>(state0, mats + 272);
    k_sel<false, 1><<<256, 64, 0, stream>>>(state0, state0, tsc, nullptr);
  }
  k_qff_exp<<<256, 64, 0, stream>>>(state0, mats + 528, qsc, sv);   // Mend + qff + expvals
  k_out<<<1, 128, 0, stream>>>(sv, W_out, b_out, out);
}